// Round 16
// baseline (301.440 us; speedup 1.0000x reference)
//
#include <hip/hip_runtime.h>
#include <cstddef>

#define N_H 8
#define N_C 32
#define N_HC 256
#define SLOPE 0.2f

typedef __attribute__((ext_vector_type(8))) short short8v;
typedef __attribute__((ext_vector_type(4))) float f32x4;

__device__ __forceinline__ short f2bf(float f) {
    unsigned u = __float_as_uint(f);
    unsigned r = (u + 0x7FFFu + ((u >> 16) & 1u)) >> 16;
    return (short)r;
}
__device__ __forceinline__ float bf2f(short s) {
    return __uint_as_float(((unsigned)(unsigned short)s) << 16);
}

// ---------- ea staging: coalesced preprocess into eap[E+1][12] (NO reduction) ----------
__global__ __launch_bounds__(256) void ea_stage_kernel(const float* __restrict__ ea,
                                                       float* __restrict__ eap, int E) {
    __shared__ float s1[256 * 11];
    const int tid = threadIdx.x;
    const int base = blockIdx.x * 256;
    const int cnt = min(256, E - base);
    const int nfl = cnt * 11;
    const int nf4 = nfl >> 2;
    for (int j = tid; j < nf4; j += 256) {
        float4 v = *(const float4*)(ea + (size_t)base * 11 + (size_t)j * 4);
        s1[j * 4 + 0] = v.x;
        s1[j * 4 + 1] = v.y;
        s1[j * 4 + 2] = v.z;
        s1[j * 4 + 3] = v.w;
    }
    for (int j = nf4 * 4 + tid; j < nfl; j += 256) s1[j] = ea[(size_t)base * 11 + j];
    __syncthreads();

    if (tid < cnt) {
        float r[11];
#pragma unroll
        for (int j = 0; j < 11; ++j) r[j] = s1[tid * 11 + j];
        if (r[9] == 1.0f) r[1] = (r[1] - r[0]) * 0.01f;
        float4* dst = (float4*)(eap + (size_t)(base + tid) * 12);
        dst[0] = {r[0], r[1], r[2], r[3]};
        dst[1] = {r[4], r[5], r[6], r[7]};
        dst[2] = {r[8], r[9], r[10], 0.f};
    }
}

// ---------- edge-attr column sums: wave-level shfl reduce, 1 barrier, 11 atomics/block ----------
__global__ __launch_bounds__(256) void ea_colsum_kernel(const float* __restrict__ ea,
                                                        float* __restrict__ sums, int E) {
    float loc[11];
#pragma unroll
    for (int j = 0; j < 11; ++j) loc[j] = 0.f;
    for (int i = blockIdx.x * blockDim.x + threadIdx.x; i < E; i += gridDim.x * blockDim.x) {
        float r[11];
#pragma unroll
        for (int j = 0; j < 11; ++j) r[j] = ea[(size_t)i * 11 + j];
        if (r[9] == 1.0f) r[1] = (r[1] - r[0]) * 0.01f;
#pragma unroll
        for (int j = 0; j < 11; ++j) loc[j] += r[j];
    }
#pragma unroll
    for (int j = 0; j < 11; ++j) {
        float v = loc[j];
        v += __shfl_xor(v, 1);
        v += __shfl_xor(v, 2);
        v += __shfl_xor(v, 4);
        v += __shfl_xor(v, 8);
        v += __shfl_xor(v, 16);
        v += __shfl_xor(v, 32);
        loc[j] = v;
    }
    __shared__ float swave[4][11];
    int wid = threadIdx.x >> 6, lane = threadIdx.x & 63;
    if (lane == 0) {
#pragma unroll
        for (int j = 0; j < 11; ++j) swave[wid][j] = loc[j];
    }
    __syncthreads();
    if (threadIdx.x < 11) {
        float v = swave[0][threadIdx.x] + swave[1][threadIdx.x] + swave[2][threadIdx.x] +
                  swave[3][threadIdx.x];
        atomicAdd(&sums[threadIdx.x], v);
    }
}

// ---------- degree histogram (int-only) ----------
__global__ __launch_bounds__(256) void deg_hist_kernel(const int* __restrict__ ei,
                                                       int* __restrict__ deg, int E, int Etot) {
    int e = blockIdx.x * blockDim.x + threadIdx.x;
    if (e >= Etot) return;
    int t = (e < E) ? ei[E + e] : e - E;
    atomicAdd(&deg[t], 1);
}

// ---------- scan (single block) + mean row into eap[E] ----------
__global__ __launch_bounds__(1024) void scan_kernel(const int* __restrict__ deg,
                                                    int* __restrict__ offs,
                                                    int* __restrict__ cursor,
                                                    const float* __restrict__ sums,
                                                    float* __restrict__ eap, int Nn, int E) {
    const int T = 1024;
    int tid = threadIdx.x;
    if (tid < 12) eap[(size_t)E * 12 + tid] = (tid < 11) ? sums[tid] / (float)E : 0.f;
    int chunk = (Nn + T - 1) / T;
    int b = tid * chunk;
    int s = 0;
    for (int k = 0; k < chunk; ++k) {
        int i = b + k;
        if (i < Nn) s += deg[i];
    }
    __shared__ int sm[T];
    sm[tid] = s;
    __syncthreads();
    for (int d = 1; d < T; d <<= 1) {
        int v = (tid >= d) ? sm[tid - d] : 0;
        __syncthreads();
        sm[tid] += v;
        __syncthreads();
    }
    int pref = (tid > 0) ? sm[tid - 1] : 0;
    for (int k = 0; k < chunk; ++k) {
        int i = b + k;
        if (i < Nn) {
            offs[i] = pref;
            cursor[i] = pref;
            pref += deg[i];
        }
    }
    if (tid == T - 1) offs[Nn] = sm[T - 1];
}

// ---------- scatter edges into CSR order (int-only) ----------
__global__ __launch_bounds__(256) void scatter_kernel(const int* __restrict__ ei,
                                                      int* __restrict__ cursor,
                                                      int* __restrict__ esrc,
                                                      int* __restrict__ eidx, int E, int Etot) {
    int e = blockIdx.x * blockDim.x + threadIdx.x;
    if (e >= Etot) return;
    int s, t;
    if (e < E) { s = ei[e]; t = ei[E + e]; }
    else       { s = t = e - E; }
    int pos = atomicAdd(&cursor[t], 1);
    esrc[pos] = s;
    eidx[pos] = (e < E) ? e : E;
}

// ---------- layer-0 node transform (K=6), x-preprocessing fused into staging ----------
template <int K, int R>
__global__ __launch_bounds__(256) void node_mm_kernel(const float* __restrict__ X,
                                                      const float* __restrict__ Wl,
                                                      const float* __restrict__ bl,
                                                      const float* __restrict__ Wr,
                                                      const float* __restrict__ br,
                                                      float* __restrict__ xl,
                                                      float* __restrict__ xr, int Nn) {
    __shared__ float xs[R][K];
    int row0 = blockIdx.x * R;
    int tid = threadIdx.x;
    for (int i = tid; i < R * K; i += blockDim.x) {
        int r = i / K, k = i - r * K;
        int gr = row0 + r;
        float v = 0.f;
        if (gr < Nn) {
            v = X[(size_t)gr * K + k];
            if (k == 1) {
                float x0 = X[(size_t)gr * K + 0];
                float x2 = X[(size_t)gr * K + 2];
                if (x2 == 1.0f) v = (v - x0) * 0.01f;
            }
        }
        xs[r][k] = v;
    }
    __syncthreads();
    int c = tid;
    float accl[R], accr[R];
#pragma unroll
    for (int r = 0; r < R; ++r) { accl[r] = bl[c]; accr[r] = br[c]; }
#pragma unroll
    for (int k = 0; k < K; ++k) {
        float wl = Wl[k * N_HC + c], wr = Wr[k * N_HC + c];
#pragma unroll
        for (int r = 0; r < R; ++r) {
            accl[r] = fmaf(xs[r][k], wl, accl[r]);
            accr[r] = fmaf(xs[r][k], wr, accr[r]);
        }
    }
#pragma unroll
    for (int r = 0; r < R; ++r) {
        int gr = row0 + r;
        if (gr < Nn) {
            xl[(size_t)gr * N_HC + c] = accl[r];
            xr[(size_t)gr * N_HC + c] = accr[r];
        }
    }
}

// ---------- convert W to MFMA-fragment-ordered split-bf16 ----------
__global__ __launch_bounds__(256) void convert_w_kernel(const float* __restrict__ Wl,
                                                        const float* __restrict__ Wr,
                                                        short* __restrict__ Bfhi,
                                                        short* __restrict__ Bflo) {
    int n = blockIdx.x;
    int k = threadIdx.x;
    float v = (n < 256) ? Wl[(size_t)k * 256 + n] : Wr[(size_t)k * 256 + (n - 256)];
    short hi = f2bf(v);
    short lo = f2bf(v - bf2f(hi));
    int cg = n >> 6, ni = (n >> 4) & 3, lm = n & 15;
    int k0 = k >> 5, lg = (k >> 3) & 3, e = k & 7;
    int lane = lg * 16 + lm;
    size_t idx = ((((size_t)cg * 8 + k0) * 4 + ni) * 64 + lane) * 8 + e;
    Bfhi[idx] = hi;
    Bflo[idx] = lo;
}

// ---------- layer-1 transform: split-bf16 MFMA GEMM, frag-ordered B (coalesced) ----------
__global__ __launch_bounds__(256) void gemm_mfma_kernel(
    const short* __restrict__ Ahi, const short* __restrict__ Alo,
    const short* __restrict__ Bfhi, const short* __restrict__ Bflo,
    const float* __restrict__ bl, const float* __restrict__ br, float* __restrict__ xl,
    float* __restrict__ xr, int Nn) {
    const int wid = threadIdx.x >> 6, lane = threadIdx.x & 63;
    const int lm = lane & 15, lg = lane >> 4;
    const int r0 = blockIdx.x * 16;
    const int half = blockIdx.y;
    const int cg = half * 4 + wid;
    const int kg = lg * 8;

    f32x4 acc0 = {0.f, 0.f, 0.f, 0.f}, acc1 = acc0, acc2 = acc0, acc3 = acc0;

    const int rA = r0 + lm;
    const bool va = rA < Nn;
    const short* pah = Ahi + (size_t)rA * 256 + kg;
    const short* pal = Alo + (size_t)rA * 256 + kg;
    const short8v zz = (short8v)0;

#pragma unroll 2
    for (int ks = 0; ks < 8; ++ks) {
        const int k0 = ks * 32;
        short8v ah = va ? *(const short8v*)(pah + k0) : zz;
        short8v al = va ? *(const short8v*)(pal + k0) : zz;
        const size_t fb = (((size_t)cg * 8 + ks) * 4) * 512 + (size_t)lane * 8;
        const short8v bh0 = *(const short8v*)(Bfhi + fb + 0 * 512);
        const short8v bl0 = *(const short8v*)(Bflo + fb + 0 * 512);
        const short8v bh1 = *(const short8v*)(Bfhi + fb + 1 * 512);
        const short8v bl1 = *(const short8v*)(Bflo + fb + 1 * 512);
        const short8v bh2 = *(const short8v*)(Bfhi + fb + 2 * 512);
        const short8v bl2 = *(const short8v*)(Bflo + fb + 2 * 512);
        const short8v bh3 = *(const short8v*)(Bfhi + fb + 3 * 512);
        const short8v bl3 = *(const short8v*)(Bflo + fb + 3 * 512);
        acc0 = __builtin_amdgcn_mfma_f32_16x16x32_bf16(ah, bh0, acc0, 0, 0, 0);
        acc0 = __builtin_amdgcn_mfma_f32_16x16x32_bf16(al, bh0, acc0, 0, 0, 0);
        acc0 = __builtin_amdgcn_mfma_f32_16x16x32_bf16(ah, bl0, acc0, 0, 0, 0);
        acc1 = __builtin_amdgcn_mfma_f32_16x16x32_bf16(ah, bh1, acc1, 0, 0, 0);
        acc1 = __builtin_amdgcn_mfma_f32_16x16x32_bf16(al, bh1, acc1, 0, 0, 0);
        acc1 = __builtin_amdgcn_mfma_f32_16x16x32_bf16(ah, bl1, acc1, 0, 0, 0);
        acc2 = __builtin_amdgcn_mfma_f32_16x16x32_bf16(ah, bh2, acc2, 0, 0, 0);
        acc2 = __builtin_amdgcn_mfma_f32_16x16x32_bf16(al, bh2, acc2, 0, 0, 0);
        acc2 = __builtin_amdgcn_mfma_f32_16x16x32_bf16(ah, bl2, acc2, 0, 0, 0);
        acc3 = __builtin_amdgcn_mfma_f32_16x16x32_bf16(ah, bh3, acc3, 0, 0, 0);
        acc3 = __builtin_amdgcn_mfma_f32_16x16x32_bf16(al, bh3, acc3, 0, 0, 0);
        acc3 = __builtin_amdgcn_mfma_f32_16x16x32_bf16(ah, bl3, acc3, 0, 0, 0);
    }

    const float* __restrict__ bias = half ? br : bl;
    float* __restrict__ dst = half ? xr : xl;
    const int clbase = wid * 64 + lm;
#pragma unroll
    for (int ni = 0; ni < 4; ++ni) {
        int col = clbase + ni * 16;
        float bv = bias[col];
        f32x4 a = (ni == 0) ? acc0 : (ni == 1) ? acc1 : (ni == 2) ? acc2 : acc3;
        int rb = r0 + lg * 4;
#pragma unroll
        for (int e = 0; e < 4; ++e) {
            int row = rb + e;
            if (row < Nn) dst[(size_t)row * N_HC + col] = a[e] + bv;
        }
    }
}

// ---------- online softmax update ----------
__device__ __forceinline__ void online_update(float logit, const float4& xlv, float& m,
                                              float& den, float4& acc) {
    float mn = fmaxf(m, logit);
    float s = __expf(m - mn);
    float w = __expf(logit - mn);
    den = den * s + w;
    acc.x = fmaf(w, xlv.x, acc.x * s);
    acc.y = fmaf(w, xlv.y, acc.y * s);
    acc.z = fmaf(w, xlv.z, acc.z * s);
    acc.w = fmaf(w, xlv.w, acc.w * s);
    m = mn;
}

// logit from gathered row; edge-attr via wave-uniform pointer (scalar loads)
template <bool L0>
__device__ __forceinline__ float edge_logit(const float4& xlv, const float4& xrv,
                                            const float4* Wreg, const float* __restrict__ eap,
                                            const float4& av) {
    float m0 = xlv.x + xrv.x, m1 = xlv.y + xrv.y, m2 = xlv.z + xrv.z, m3 = xlv.w + xrv.w;
    if (L0) {
#pragma unroll
        for (int j = 0; j < 11; ++j) {
            float aj = eap[j];
            m0 = fmaf(aj, Wreg[j].x, m0);
            m1 = fmaf(aj, Wreg[j].y, m1);
            m2 = fmaf(aj, Wreg[j].z, m2);
            m3 = fmaf(aj, Wreg[j].w, m3);
        }
    }
    m0 = m0 > 0.f ? m0 : SLOPE * m0;
    m1 = m1 > 0.f ? m1 : SLOPE * m1;
    m2 = m2 > 0.f ? m2 : SLOPE * m2;
    m3 = m3 > 0.f ? m3 : SLOPE * m3;
    float p = m0 * av.x + m1 * av.y + m2 * av.z + m3 * av.w;
    p += __shfl_xor(p, 1);
    p += __shfl_xor(p, 2);
    p += __shfl_xor(p, 4);
    return p;
}

// ---------- fused per-node gather: 2-deep software pipeline, named registers ----------
// If oAhi != null, output is written as split bf16 (Ahi/Alo) instead of f32 `out`.
template <bool L0>
__global__ __launch_bounds__(256) void node_gather_kernel(
    const int* __restrict__ offs, const int* __restrict__ esrc, const int* __restrict__ eidx,
    const float* __restrict__ eap, const float* __restrict__ We,
    const float* __restrict__ att, const float* __restrict__ xl, const float* __restrict__ xr,
    const float* __restrict__ bias, float* __restrict__ out, short* __restrict__ oAhi,
    short* __restrict__ oAlo, int Nn) {
    int wid = threadIdx.x >> 6;
    int lane = threadIdx.x & 63;
    int node = blockIdx.x * 4 + wid;
    if (node >= Nn) return;
    int c4 = lane * 4;

    float4 Wreg[11];
    if (L0) {
#pragma unroll
        for (int j = 0; j < 11; ++j) Wreg[j] = *(const float4*)(We + j * N_HC + c4);
    }
    const float4 xrv = *(const float4*)(xr + (size_t)node * N_HC + c4);
    const float4 av = *(const float4*)(att + c4);

    int beg = offs[node], end = offs[node + 1];
    int nfull = (end - beg) >> 2;

    float mA = -INFINITY, dA = 0.f;
    float mB = -INFINITY, dB = 0.f;
    float mC = -INFINITY, dC = 0.f;
    float mD = -INFINITY, dD = 0.f;
    float4 aA = {0.f, 0.f, 0.f, 0.f}, aB = aA, aC = aA, aD = aA;

    int p = beg;

    // named register sets for 2-deep pipeline
    float4 xa0, xa1, xa2, xa3;
    float4 xb0, xb1, xb2, xb3;

#define LOAD_SET(v0, v1, v2, v3, pp)                                          \
    {                                                                         \
        int pu_ = __builtin_amdgcn_readfirstlane(pp);                         \
        int t0_ = esrc[pu_ + 0];                                              \
        int t1_ = esrc[pu_ + 1];                                              \
        int t2_ = esrc[pu_ + 2];                                              \
        int t3_ = esrc[pu_ + 3];                                              \
        v0 = *(const float4*)(xl + (size_t)t0_ * N_HC + c4);                  \
        v1 = *(const float4*)(xl + (size_t)t1_ * N_HC + c4);                  \
        v2 = *(const float4*)(xl + (size_t)t2_ * N_HC + c4);                  \
        v3 = *(const float4*)(xl + (size_t)t3_ * N_HC + c4);                  \
    }

#define CONSUME_SET(v0, v1, v2, v3, pp)                                       \
    {                                                                         \
        int pu_ = __builtin_amdgcn_readfirstlane(pp);                         \
        const float *e0_ = nullptr, *e1_ = nullptr, *e2_ = nullptr,           \
                    *e3_ = nullptr;                                           \
        if (L0) {                                                             \
            e0_ = eap + (size_t)eidx[pu_ + 0] * 12;                           \
            e1_ = eap + (size_t)eidx[pu_ + 1] * 12;                           \
            e2_ = eap + (size_t)eidx[pu_ + 2] * 12;                           \
            e3_ = eap + (size_t)eidx[pu_ + 3] * 12;                           \
        }                                                                     \
        float lg0_ = edge_logit<L0>(v0, xrv, Wreg, e0_, av);                  \
        float lg1_ = edge_logit<L0>(v1, xrv, Wreg, e1_, av);                  \
        float lg2_ = edge_logit<L0>(v2, xrv, Wreg, e2_, av);                  \
        float lg3_ = edge_logit<L0>(v3, xrv, Wreg, e3_, av);                  \
        online_update(lg0_, v0, mA, dA, aA);                                  \
        online_update(lg1_, v1, mB, dB, aB);                                  \
        online_update(lg2_, v2, mC, dC, aC);                                  \
        online_update(lg3_, v3, mD, dD, aD);                                  \
    }

    if (nfull > 0) LOAD_SET(xa0, xa1, xa2, xa3, p);
    int i = 0;
    for (; i + 1 < nfull; i += 2) {
        LOAD_SET(xb0, xb1, xb2, xb3, p + 4);
        CONSUME_SET(xa0, xa1, xa2, xa3, p);
        p += 4;
        if (i + 2 < nfull) LOAD_SET(xa0, xa1, xa2, xa3, p + 4);
        CONSUME_SET(xb0, xb1, xb2, xb3, p);
        p += 4;
    }
    if (i < nfull) {
        CONSUME_SET(xa0, xa1, xa2, xa3, p);
        p += 4;
    }
#undef LOAD_SET
#undef CONSUME_SET

    // scalar tail (<4 edges)
    for (; p < end; ++p) {
        int pu = __builtin_amdgcn_readfirstlane(p);
        int s0 = esrc[pu];
        const float4 x0 = *(const float4*)(xl + (size_t)s0 * N_HC + c4);
        const float* e0 = L0 ? (eap + (size_t)eidx[pu] * 12) : nullptr;
        float lg0 = edge_logit<L0>(x0, xrv, Wreg, e0, av);
        online_update(lg0, x0, mA, dA, aA);
    }

    // merge 4 states
    float mm = fmaxf(fmaxf(mA, mB), fmaxf(mC, mD));
    float sA = __expf(mA - mm), sB = __expf(mB - mm);
    float sC = __expf(mC - mm), sD = __expf(mD - mm);
    float den = dA * sA + dB * sB + dC * sC + dD * sD;
    float4 acct;
    acct.x = aA.x * sA + aB.x * sB + aC.x * sC + aD.x * sD;
    acct.y = aA.y * sA + aB.y * sB + aC.y * sC + aD.y * sD;
    acct.z = aA.z * sA + aB.z * sB + aC.z * sC + aD.z * sD;
    acct.w = aA.w * sA + aB.w * sB + aC.w * sC + aD.w * sD;

    const float4 bv = *(const float4*)(bias + c4);
    float4 r;
    r.x = acct.x / den + bv.x;
    r.y = acct.y / den + bv.y;
    r.z = acct.z / den + bv.z;
    r.w = acct.w / den + bv.w;
    if (L0) {
        r.x = r.x > 0.f ? r.x : (__expf(r.x) - 1.f);
        r.y = r.y > 0.f ? r.y : (__expf(r.y) - 1.f);
        r.z = r.z > 0.f ? r.z : (__expf(r.z) - 1.f);
        r.w = r.w > 0.f ? r.w : (__expf(r.w) - 1.f);
    }
    if (oAhi) {
        short h0 = f2bf(r.x), h1 = f2bf(r.y), h2 = f2bf(r.z), h3 = f2bf(r.w);
        short4 hv = {h0, h1, h2, h3};
        short4 lv = {f2bf(r.x - bf2f(h0)), f2bf(r.y - bf2f(h1)), f2bf(r.z - bf2f(h2)),
                     f2bf(r.w - bf2f(h3))};
        *(short4*)(oAhi + (size_t)node * N_HC + c4) = hv;
        *(short4*)(oAlo + (size_t)node * N_HC + c4) = lv;
    } else {
        *(float4*)(out + (size_t)node * N_HC + c4) = r;
    }
}

extern "C" void kernel_launch(void* const* d_in, const int* in_sizes, int n_in, void* d_out,
                              int out_size, void* d_ws, size_t ws_size, hipStream_t stream) {
    const float* x = (const float*)d_in[0];
    const int* ei = (const int*)d_in[1];
    const float* ea = (const float*)d_in[2];
    const float* Wl0 = (const float*)d_in[3];
    const float* bl0 = (const float*)d_in[4];
    const float* Wr0 = (const float*)d_in[5];
    const float* br0 = (const float*)d_in[6];
    const float* We0 = (const float*)d_in[7];
    const float* att0 = (const float*)d_in[8];
    const float* bias0 = (const float*)d_in[9];
    const float* Wl1 = (const float*)d_in[10];
    const float* bl1 = (const float*)d_in[11];
    const float* Wr1 = (const float*)d_in[12];
    const float* br1 = (const float*)d_in[13];
    const float* att1 = (const float*)d_in[14];
    const float* bias1 = (const float*)d_in[15];
    float* out = (float*)d_out;

    const int Nn = in_sizes[0] / 6;
    const int E = in_sizes[1] / 2;
    const int Etot = E + Nn;

    auto align16 = [](size_t v) { return (v + 15) & ~(size_t)15; };
    float* ws = (float*)d_ws;
    size_t o = 0;
    float* xl = ws + o;    o = align16(o + (size_t)Nn * N_HC);
    float* xr = ws + o;    o = align16(o + (size_t)Nn * N_HC);
    float* h = ws + o;     o = align16(o + (size_t)Nn * N_HC);
    float* eap = ws + o;   o = align16(o + (size_t)(E + 1) * 12);
    float* easum = ws + o; o = align16(o + 16);
    int* deg = (int*)(ws + o);    o = align16(o + (size_t)Nn);
    int* offs = (int*)(ws + o);   o = align16(o + (size_t)Nn + 1);
    int* cursor = (int*)(ws + o); o = align16(o + (size_t)Nn);
    int* esrc = (int*)(ws + o);   o = align16(o + (size_t)Etot);
    int* eidx = (int*)(ws + o);   o = align16(o + (size_t)Etot);
    short* Bfhi = (short*)(ws + o); o = align16(o + 512 * 256 / 2);
    short* Bflo = (short*)(ws + o); o = align16(o + 512 * 256 / 2);
    const bool use_mfma = (o * sizeof(float) <= ws_size);

    hipMemsetAsync(easum, 0, 16 * sizeof(float), stream);
    hipMemsetAsync(deg, 0, (size_t)Nn * sizeof(int), stream);

    // edge-attr: streaming preprocess + low-overhead column sums
    ea_stage_kernel<<<(E + 255) / 256, 256, 0, stream>>>(ea, eap, E);
    ea_colsum_kernel<<<64, 256, 0, stream>>>(ea, easum, E);
    // CSR build (int-only) + mean row
    deg_hist_kernel<<<(Etot + 255) / 256, 256, 0, stream>>>(ei, deg, E, Etot);
    scan_kernel<<<1, 1024, 0, stream>>>(deg, offs, cursor, easum, eap, Nn, E);
    scatter_kernel<<<(Etot + 255) / 256, 256, 0, stream>>>(ei, cursor, esrc, eidx, E, Etot);

    const int gblocks = (Nn + 3) / 4;

    short* Ahi = (short*)d_out;               // scratch in d_out, dead until gather L1
    short* Alo = Ahi + (size_t)Nn * N_HC;

    // layer 0 (gather writes split-bf16 h directly when MFMA path is active)
    node_mm_kernel<6, 8><<<(Nn + 7) / 8, 256, 0, stream>>>(x, Wl0, bl0, Wr0, br0, xl, xr, Nn);
    node_gather_kernel<true><<<gblocks, 256, 0, stream>>>(offs, esrc, eidx, eap, We0, att0, xl,
                                                          xr, bias0, h, use_mfma ? Ahi : nullptr,
                                                          use_mfma ? Alo : nullptr, Nn);

    // layer 1 transform
    if (use_mfma) {
        convert_w_kernel<<<512, 256, 0, stream>>>(Wl1, Wr1, Bfhi, Bflo);
        dim3 mgrid((Nn + 15) / 16, 2);
        gemm_mfma_kernel<<<mgrid, 256, 0, stream>>>(Ahi, Alo, Bfhi, Bflo, bl1, br1, xl, xr, Nn);
    } else {
        node_mm_kernel<256, 8><<<(Nn + 7) / 8, 256, 0, stream>>>(h, Wl1, bl1, Wr1, br1, xl, xr,
                                                                 Nn);
    }
    node_gather_kernel<false><<<gblocks, 256, 0, stream>>>(offs, esrc, nullptr, nullptr, nullptr,
                                                           att1, xl, xr, bias1, out, nullptr,
                                                           nullptr, Nn);
}

// Round 17
// 270.302 us; speedup vs baseline: 1.1152x; 1.1152x over previous
//
#include <hip/hip_runtime.h>
#include <cstddef>

#define N_H 8
#define N_C 32
#define N_HC 256
#define SLOPE 0.2f

typedef __attribute__((ext_vector_type(8))) short short8v;
typedef __attribute__((ext_vector_type(4))) float f32x4;

__device__ __forceinline__ short f2bf(float f) {
    unsigned u = __float_as_uint(f);
    unsigned r = (u + 0x7FFFu + ((u >> 16) & 1u)) >> 16;
    return (short)r;
}
__device__ __forceinline__ float bf2f(short s) {
    return __uint_as_float(((unsigned)(unsigned short)s) << 16);
}

// ---------- ea staging: coalesced preprocess into eap[E+1][12] (NO reduction) ----------
__global__ __launch_bounds__(256) void ea_stage_kernel(const float* __restrict__ ea,
                                                       float* __restrict__ eap, int E) {
    __shared__ float s1[256 * 11];
    const int tid = threadIdx.x;
    const int base = blockIdx.x * 256;
    const int cnt = min(256, E - base);
    const int nfl = cnt * 11;
    const int nf4 = nfl >> 2;
    for (int j = tid; j < nf4; j += 256) {
        float4 v = *(const float4*)(ea + (size_t)base * 11 + (size_t)j * 4);
        s1[j * 4 + 0] = v.x;
        s1[j * 4 + 1] = v.y;
        s1[j * 4 + 2] = v.z;
        s1[j * 4 + 3] = v.w;
    }
    for (int j = nf4 * 4 + tid; j < nfl; j += 256) s1[j] = ea[(size_t)base * 11 + j];
    __syncthreads();

    if (tid < cnt) {
        float r[11];
#pragma unroll
        for (int j = 0; j < 11; ++j) r[j] = s1[tid * 11 + j];
        if (r[9] == 1.0f) r[1] = (r[1] - r[0]) * 0.01f;
        float4* dst = (float4*)(eap + (size_t)(base + tid) * 12);
        dst[0] = {r[0], r[1], r[2], r[3]};
        dst[1] = {r[4], r[5], r[6], r[7]};
        dst[2] = {r[8], r[9], r[10], 0.f};
    }
}

// ---------- edge-attr column sums: wave-level shfl reduce, 1 barrier, 11 atomics/block ----------
__global__ __launch_bounds__(256) void ea_colsum_kernel(const float* __restrict__ ea,
                                                        float* __restrict__ sums, int E) {
    float loc[11];
#pragma unroll
    for (int j = 0; j < 11; ++j) loc[j] = 0.f;
    for (int i = blockIdx.x * blockDim.x + threadIdx.x; i < E; i += gridDim.x * blockDim.x) {
        float r[11];
#pragma unroll
        for (int j = 0; j < 11; ++j) r[j] = ea[(size_t)i * 11 + j];
        if (r[9] == 1.0f) r[1] = (r[1] - r[0]) * 0.01f;
#pragma unroll
        for (int j = 0; j < 11; ++j) loc[j] += r[j];
    }
#pragma unroll
    for (int j = 0; j < 11; ++j) {
        float v = loc[j];
        v += __shfl_xor(v, 1);
        v += __shfl_xor(v, 2);
        v += __shfl_xor(v, 4);
        v += __shfl_xor(v, 8);
        v += __shfl_xor(v, 16);
        v += __shfl_xor(v, 32);
        loc[j] = v;
    }
    __shared__ float swave[4][11];
    int wid = threadIdx.x >> 6, lane = threadIdx.x & 63;
    if (lane == 0) {
#pragma unroll
        for (int j = 0; j < 11; ++j) swave[wid][j] = loc[j];
    }
    __syncthreads();
    if (threadIdx.x < 11) {
        float v = swave[0][threadIdx.x] + swave[1][threadIdx.x] + swave[2][threadIdx.x] +
                  swave[3][threadIdx.x];
        atomicAdd(&sums[threadIdx.x], v);
    }
}

// ---------- degree histogram (int-only) ----------
__global__ __launch_bounds__(256) void deg_hist_kernel(const int* __restrict__ ei,
                                                       int* __restrict__ deg, int E, int Etot) {
    int e = blockIdx.x * blockDim.x + threadIdx.x;
    if (e >= Etot) return;
    int t = (e < E) ? ei[E + e] : e - E;
    atomicAdd(&deg[t], 1);
}

// ---------- scan (single block) + mean row into eap[E] ----------
__global__ __launch_bounds__(1024) void scan_kernel(const int* __restrict__ deg,
                                                    int* __restrict__ offs,
                                                    int* __restrict__ cursor,
                                                    const float* __restrict__ sums,
                                                    float* __restrict__ eap, int Nn, int E) {
    const int T = 1024;
    int tid = threadIdx.x;
    if (tid < 12) eap[(size_t)E * 12 + tid] = (tid < 11) ? sums[tid] / (float)E : 0.f;
    int chunk = (Nn + T - 1) / T;
    int b = tid * chunk;
    int s = 0;
    for (int k = 0; k < chunk; ++k) {
        int i = b + k;
        if (i < Nn) s += deg[i];
    }
    __shared__ int sm[T];
    sm[tid] = s;
    __syncthreads();
    for (int d = 1; d < T; d <<= 1) {
        int v = (tid >= d) ? sm[tid - d] : 0;
        __syncthreads();
        sm[tid] += v;
        __syncthreads();
    }
    int pref = (tid > 0) ? sm[tid - 1] : 0;
    for (int k = 0; k < chunk; ++k) {
        int i = b + k;
        if (i < Nn) {
            offs[i] = pref;
            cursor[i] = pref;
            pref += deg[i];
        }
    }
    if (tid == T - 1) offs[Nn] = sm[T - 1];
}

// ---------- scatter edges into CSR order (int-only) ----------
__global__ __launch_bounds__(256) void scatter_kernel(const int* __restrict__ ei,
                                                      int* __restrict__ cursor,
                                                      int* __restrict__ esrc,
                                                      int* __restrict__ eidx, int E, int Etot) {
    int e = blockIdx.x * blockDim.x + threadIdx.x;
    if (e >= Etot) return;
    int s, t;
    if (e < E) { s = ei[e]; t = ei[E + e]; }
    else       { s = t = e - E; }
    int pos = atomicAdd(&cursor[t], 1);
    esrc[pos] = s;
    eidx[pos] = (e < E) ? e : E;
}

// ---------- layer-0 node transform (K=6), x-preprocessing fused into staging ----------
template <int K, int R>
__global__ __launch_bounds__(256) void node_mm_kernel(const float* __restrict__ X,
                                                      const float* __restrict__ Wl,
                                                      const float* __restrict__ bl,
                                                      const float* __restrict__ Wr,
                                                      const float* __restrict__ br,
                                                      float* __restrict__ xl,
                                                      float* __restrict__ xr, int Nn) {
    __shared__ float xs[R][K];
    int row0 = blockIdx.x * R;
    int tid = threadIdx.x;
    for (int i = tid; i < R * K; i += blockDim.x) {
        int r = i / K, k = i - r * K;
        int gr = row0 + r;
        float v = 0.f;
        if (gr < Nn) {
            v = X[(size_t)gr * K + k];
            if (k == 1) {
                float x0 = X[(size_t)gr * K + 0];
                float x2 = X[(size_t)gr * K + 2];
                if (x2 == 1.0f) v = (v - x0) * 0.01f;
            }
        }
        xs[r][k] = v;
    }
    __syncthreads();
    int c = tid;
    float accl[R], accr[R];
#pragma unroll
    for (int r = 0; r < R; ++r) { accl[r] = bl[c]; accr[r] = br[c]; }
#pragma unroll
    for (int k = 0; k < K; ++k) {
        float wl = Wl[k * N_HC + c], wr = Wr[k * N_HC + c];
#pragma unroll
        for (int r = 0; r < R; ++r) {
            accl[r] = fmaf(xs[r][k], wl, accl[r]);
            accr[r] = fmaf(xs[r][k], wr, accr[r]);
        }
    }
#pragma unroll
    for (int r = 0; r < R; ++r) {
        int gr = row0 + r;
        if (gr < Nn) {
            xl[(size_t)gr * N_HC + c] = accl[r];
            xr[(size_t)gr * N_HC + c] = accr[r];
        }
    }
}

// ---------- convert W to MFMA-fragment-ordered split-bf16 ----------
__global__ __launch_bounds__(256) void convert_w_kernel(const float* __restrict__ Wl,
                                                        const float* __restrict__ Wr,
                                                        short* __restrict__ Bfhi,
                                                        short* __restrict__ Bflo) {
    int n = blockIdx.x;
    int k = threadIdx.x;
    float v = (n < 256) ? Wl[(size_t)k * 256 + n] : Wr[(size_t)k * 256 + (n - 256)];
    short hi = f2bf(v);
    short lo = f2bf(v - bf2f(hi));
    int cg = n >> 6, ni = (n >> 4) & 3, lm = n & 15;
    int k0 = k >> 5, lg = (k >> 3) & 3, e = k & 7;
    int lane = lg * 16 + lm;
    size_t idx = ((((size_t)cg * 8 + k0) * 4 + ni) * 64 + lane) * 8 + e;
    Bfhi[idx] = hi;
    Bflo[idx] = lo;
}

// ---------- layer-1 transform: split-bf16 MFMA GEMM, frag-ordered B (coalesced) ----------
__global__ __launch_bounds__(256) void gemm_mfma_kernel(
    const short* __restrict__ Ahi, const short* __restrict__ Alo,
    const short* __restrict__ Bfhi, const short* __restrict__ Bflo,
    const float* __restrict__ bl, const float* __restrict__ br, float* __restrict__ xl,
    float* __restrict__ xr, int Nn) {
    const int wid = threadIdx.x >> 6, lane = threadIdx.x & 63;
    const int lm = lane & 15, lg = lane >> 4;
    const int r0 = blockIdx.x * 16;
    const int half = blockIdx.y;
    const int cg = half * 4 + wid;
    const int kg = lg * 8;

    f32x4 acc0 = {0.f, 0.f, 0.f, 0.f}, acc1 = acc0, acc2 = acc0, acc3 = acc0;

    const int rA = r0 + lm;
    const bool va = rA < Nn;
    const short* pah = Ahi + (size_t)rA * 256 + kg;
    const short* pal = Alo + (size_t)rA * 256 + kg;
    const short8v zz = (short8v)0;

#pragma unroll 2
    for (int ks = 0; ks < 8; ++ks) {
        const int k0 = ks * 32;
        short8v ah = va ? *(const short8v*)(pah + k0) : zz;
        short8v al = va ? *(const short8v*)(pal + k0) : zz;
        const size_t fb = (((size_t)cg * 8 + ks) * 4) * 512 + (size_t)lane * 8;
        const short8v bh0 = *(const short8v*)(Bfhi + fb + 0 * 512);
        const short8v bl0 = *(const short8v*)(Bflo + fb + 0 * 512);
        const short8v bh1 = *(const short8v*)(Bfhi + fb + 1 * 512);
        const short8v bl1 = *(const short8v*)(Bflo + fb + 1 * 512);
        const short8v bh2 = *(const short8v*)(Bfhi + fb + 2 * 512);
        const short8v bl2 = *(const short8v*)(Bflo + fb + 2 * 512);
        const short8v bh3 = *(const short8v*)(Bfhi + fb + 3 * 512);
        const short8v bl3 = *(const short8v*)(Bflo + fb + 3 * 512);
        acc0 = __builtin_amdgcn_mfma_f32_16x16x32_bf16(ah, bh0, acc0, 0, 0, 0);
        acc0 = __builtin_amdgcn_mfma_f32_16x16x32_bf16(al, bh0, acc0, 0, 0, 0);
        acc0 = __builtin_amdgcn_mfma_f32_16x16x32_bf16(ah, bl0, acc0, 0, 0, 0);
        acc1 = __builtin_amdgcn_mfma_f32_16x16x32_bf16(ah, bh1, acc1, 0, 0, 0);
        acc1 = __builtin_amdgcn_mfma_f32_16x16x32_bf16(al, bh1, acc1, 0, 0, 0);
        acc1 = __builtin_amdgcn_mfma_f32_16x16x32_bf16(ah, bl1, acc1, 0, 0, 0);
        acc2 = __builtin_amdgcn_mfma_f32_16x16x32_bf16(ah, bh2, acc2, 0, 0, 0);
        acc2 = __builtin_amdgcn_mfma_f32_16x16x32_bf16(al, bh2, acc2, 0, 0, 0);
        acc2 = __builtin_amdgcn_mfma_f32_16x16x32_bf16(ah, bl2, acc2, 0, 0, 0);
        acc3 = __builtin_amdgcn_mfma_f32_16x16x32_bf16(ah, bh3, acc3, 0, 0, 0);
        acc3 = __builtin_amdgcn_mfma_f32_16x16x32_bf16(al, bh3, acc3, 0, 0, 0);
        acc3 = __builtin_amdgcn_mfma_f32_16x16x32_bf16(ah, bl3, acc3, 0, 0, 0);
    }

    const float* __restrict__ bias = half ? br : bl;
    float* __restrict__ dst = half ? xr : xl;
    const int clbase = wid * 64 + lm;
#pragma unroll
    for (int ni = 0; ni < 4; ++ni) {
        int col = clbase + ni * 16;
        float bv = bias[col];
        f32x4 a = (ni == 0) ? acc0 : (ni == 1) ? acc1 : (ni == 2) ? acc2 : acc3;
        int rb = r0 + lg * 4;
#pragma unroll
        for (int e = 0; e < 4; ++e) {
            int row = rb + e;
            if (row < Nn) dst[(size_t)row * N_HC + col] = a[e] + bv;
        }
    }
}

// ---------- online softmax update ----------
__device__ __forceinline__ void online_update(float logit, const float4& xlv, float& m,
                                              float& den, float4& acc) {
    float mn = fmaxf(m, logit);
    float s = __expf(m - mn);
    float w = __expf(logit - mn);
    den = den * s + w;
    acc.x = fmaf(w, xlv.x, acc.x * s);
    acc.y = fmaf(w, xlv.y, acc.y * s);
    acc.z = fmaf(w, xlv.z, acc.z * s);
    acc.w = fmaf(w, xlv.w, acc.w * s);
    m = mn;
}

// logit from gathered row; edge-attr via wave-uniform pointer (scalar loads)
template <bool L0>
__device__ __forceinline__ float edge_logit(const float4& xlv, const float4& xrv,
                                            const float4* Wreg, const float* __restrict__ eap,
                                            const float4& av) {
    float m0 = xlv.x + xrv.x, m1 = xlv.y + xrv.y, m2 = xlv.z + xrv.z, m3 = xlv.w + xrv.w;
    if (L0) {
#pragma unroll
        for (int j = 0; j < 11; ++j) {
            float aj = eap[j];
            m0 = fmaf(aj, Wreg[j].x, m0);
            m1 = fmaf(aj, Wreg[j].y, m1);
            m2 = fmaf(aj, Wreg[j].z, m2);
            m3 = fmaf(aj, Wreg[j].w, m3);
        }
    }
    m0 = m0 > 0.f ? m0 : SLOPE * m0;
    m1 = m1 > 0.f ? m1 : SLOPE * m1;
    m2 = m2 > 0.f ? m2 : SLOPE * m2;
    m3 = m3 > 0.f ? m3 : SLOPE * m3;
    float p = m0 * av.x + m1 * av.y + m2 * av.z + m3 * av.w;
    p += __shfl_xor(p, 1);
    p += __shfl_xor(p, 2);
    p += __shfl_xor(p, 4);
    return p;
}

// ---------- fused per-node gather: 4 named states, 4 loads in flight (R15/R9 structure) ----------
// If oAhi != null, output is written as split bf16 (Ahi/Alo) instead of f32 `out`.
template <bool L0>
__global__ __launch_bounds__(256) void node_gather_kernel(
    const int* __restrict__ offs, const int* __restrict__ esrc, const int* __restrict__ eidx,
    const float* __restrict__ eap, const float* __restrict__ We,
    const float* __restrict__ att, const float* __restrict__ xl, const float* __restrict__ xr,
    const float* __restrict__ bias, float* __restrict__ out, short* __restrict__ oAhi,
    short* __restrict__ oAlo, int Nn) {
    int wid = threadIdx.x >> 6;
    int lane = threadIdx.x & 63;
    int node = blockIdx.x * 4 + wid;
    if (node >= Nn) return;
    int c4 = lane * 4;

    float4 Wreg[11];
    if (L0) {
#pragma unroll
        for (int j = 0; j < 11; ++j) Wreg[j] = *(const float4*)(We + j * N_HC + c4);
    }
    const float4 xrv = *(const float4*)(xr + (size_t)node * N_HC + c4);
    const float4 av = *(const float4*)(att + c4);

    int beg = offs[node], end = offs[node + 1];

    float mA = -INFINITY, dA = 0.f;
    float mB = -INFINITY, dB = 0.f;
    float mC = -INFINITY, dC = 0.f;
    float mD = -INFINITY, dD = 0.f;
    float4 aA = {0.f, 0.f, 0.f, 0.f}, aB = aA, aC = aA, aD = aA;

    int p = beg;
    for (; p + 3 < end; p += 4) {
        int pu = __builtin_amdgcn_readfirstlane(p);
        int s0 = esrc[pu + 0];
        int s1 = esrc[pu + 1];
        int s2 = esrc[pu + 2];
        int s3 = esrc[pu + 3];
        const float4 x0 = *(const float4*)(xl + (size_t)s0 * N_HC + c4);
        const float4 x1 = *(const float4*)(xl + (size_t)s1 * N_HC + c4);
        const float4 x2 = *(const float4*)(xl + (size_t)s2 * N_HC + c4);
        const float4 x3 = *(const float4*)(xl + (size_t)s3 * N_HC + c4);
        const float *e0 = nullptr, *e1 = nullptr, *e2 = nullptr, *e3 = nullptr;
        if (L0) {
            e0 = eap + (size_t)eidx[pu + 0] * 12;
            e1 = eap + (size_t)eidx[pu + 1] * 12;
            e2 = eap + (size_t)eidx[pu + 2] * 12;
            e3 = eap + (size_t)eidx[pu + 3] * 12;
        }
        float lg0 = edge_logit<L0>(x0, xrv, Wreg, e0, av);
        float lg1 = edge_logit<L0>(x1, xrv, Wreg, e1, av);
        float lg2 = edge_logit<L0>(x2, xrv, Wreg, e2, av);
        float lg3 = edge_logit<L0>(x3, xrv, Wreg, e3, av);
        online_update(lg0, x0, mA, dA, aA);
        online_update(lg1, x1, mB, dB, aB);
        online_update(lg2, x2, mC, dC, aC);
        online_update(lg3, x3, mD, dD, aD);
    }
    for (; p < end; ++p) {
        int pu = __builtin_amdgcn_readfirstlane(p);
        int s0 = esrc[pu];
        const float4 x0 = *(const float4*)(xl + (size_t)s0 * N_HC + c4);
        const float* e0 = L0 ? (eap + (size_t)eidx[pu] * 12) : nullptr;
        float lg0 = edge_logit<L0>(x0, xrv, Wreg, e0, av);
        online_update(lg0, x0, mA, dA, aA);
    }

    // merge 4 states
    float mm = fmaxf(fmaxf(mA, mB), fmaxf(mC, mD));
    float sA = __expf(mA - mm), sB = __expf(mB - mm);
    float sC = __expf(mC - mm), sD = __expf(mD - mm);
    float den = dA * sA + dB * sB + dC * sC + dD * sD;
    float4 acct;
    acct.x = aA.x * sA + aB.x * sB + aC.x * sC + aD.x * sD;
    acct.y = aA.y * sA + aB.y * sB + aC.y * sC + aD.y * sD;
    acct.z = aA.z * sA + aB.z * sB + aC.z * sC + aD.z * sD;
    acct.w = aA.w * sA + aB.w * sB + aC.w * sC + aD.w * sD;

    const float4 bv = *(const float4*)(bias + c4);
    float4 r;
    r.x = acct.x / den + bv.x;
    r.y = acct.y / den + bv.y;
    r.z = acct.z / den + bv.z;
    r.w = acct.w / den + bv.w;
    if (L0) {
        r.x = r.x > 0.f ? r.x : (__expf(r.x) - 1.f);
        r.y = r.y > 0.f ? r.y : (__expf(r.y) - 1.f);
        r.z = r.z > 0.f ? r.z : (__expf(r.z) - 1.f);
        r.w = r.w > 0.f ? r.w : (__expf(r.w) - 1.f);
    }
    if (oAhi) {
        short h0 = f2bf(r.x), h1 = f2bf(r.y), h2 = f2bf(r.z), h3 = f2bf(r.w);
        short4 hv = {h0, h1, h2, h3};
        short4 lv = {f2bf(r.x - bf2f(h0)), f2bf(r.y - bf2f(h1)), f2bf(r.z - bf2f(h2)),
                     f2bf(r.w - bf2f(h3))};
        *(short4*)(oAhi + (size_t)node * N_HC + c4) = hv;
        *(short4*)(oAlo + (size_t)node * N_HC + c4) = lv;
    } else {
        *(float4*)(out + (size_t)node * N_HC + c4) = r;
    }
}

extern "C" void kernel_launch(void* const* d_in, const int* in_sizes, int n_in, void* d_out,
                              int out_size, void* d_ws, size_t ws_size, hipStream_t stream) {
    const float* x = (const float*)d_in[0];
    const int* ei = (const int*)d_in[1];
    const float* ea = (const float*)d_in[2];
    const float* Wl0 = (const float*)d_in[3];
    const float* bl0 = (const float*)d_in[4];
    const float* Wr0 = (const float*)d_in[5];
    const float* br0 = (const float*)d_in[6];
    const float* We0 = (const float*)d_in[7];
    const float* att0 = (const float*)d_in[8];
    const float* bias0 = (const float*)d_in[9];
    const float* Wl1 = (const float*)d_in[10];
    const float* bl1 = (const float*)d_in[11];
    const float* Wr1 = (const float*)d_in[12];
    const float* br1 = (const float*)d_in[13];
    const float* att1 = (const float*)d_in[14];
    const float* bias1 = (const float*)d_in[15];
    float* out = (float*)d_out;

    const int Nn = in_sizes[0] / 6;
    const int E = in_sizes[1] / 2;
    const int Etot = E + Nn;

    auto align16 = [](size_t v) { return (v + 15) & ~(size_t)15; };
    float* ws = (float*)d_ws;
    size_t o = 0;
    float* xl = ws + o;    o = align16(o + (size_t)Nn * N_HC);
    float* xr = ws + o;    o = align16(o + (size_t)Nn * N_HC);
    float* h = ws + o;     o = align16(o + (size_t)Nn * N_HC);
    float* eap = ws + o;   o = align16(o + (size_t)(E + 1) * 12);
    float* easum = ws + o; o = align16(o + 16);
    int* deg = (int*)(ws + o);    o = align16(o + (size_t)Nn);
    int* offs = (int*)(ws + o);   o = align16(o + (size_t)Nn + 1);
    int* cursor = (int*)(ws + o); o = align16(o + (size_t)Nn);
    int* esrc = (int*)(ws + o);   o = align16(o + (size_t)Etot);
    int* eidx = (int*)(ws + o);   o = align16(o + (size_t)Etot);
    short* Bfhi = (short*)(ws + o); o = align16(o + 512 * 256 / 2);
    short* Bflo = (short*)(ws + o); o = align16(o + 512 * 256 / 2);
    const bool use_mfma = (o * sizeof(float) <= ws_size);

    hipMemsetAsync(easum, 0, 16 * sizeof(float), stream);
    hipMemsetAsync(deg, 0, (size_t)Nn * sizeof(int), stream);

    // edge-attr: streaming preprocess + low-overhead column sums
    ea_stage_kernel<<<(E + 255) / 256, 256, 0, stream>>>(ea, eap, E);
    ea_colsum_kernel<<<64, 256, 0, stream>>>(ea, easum, E);
    // CSR build (int-only) + mean row
    deg_hist_kernel<<<(Etot + 255) / 256, 256, 0, stream>>>(ei, deg, E, Etot);
    scan_kernel<<<1, 1024, 0, stream>>>(deg, offs, cursor, easum, eap, Nn, E);
    scatter_kernel<<<(Etot + 255) / 256, 256, 0, stream>>>(ei, cursor, esrc, eidx, E, Etot);

    const int gblocks = (Nn + 3) / 4;

    short* Ahi = (short*)d_out;               // scratch in d_out, dead until gather L1
    short* Alo = Ahi + (size_t)Nn * N_HC;

    // layer 0 (gather writes split-bf16 h directly when MFMA path is active)
    node_mm_kernel<6, 8><<<(Nn + 7) / 8, 256, 0, stream>>>(x, Wl0, bl0, Wr0, br0, xl, xr, Nn);
    node_gather_kernel<true><<<gblocks, 256, 0, stream>>>(offs, esrc, eidx, eap, We0, att0, xl,
                                                          xr, bias0, h, use_mfma ? Ahi : nullptr,
                                                          use_mfma ? Alo : nullptr, Nn);

    // layer 1 transform
    if (use_mfma) {
        convert_w_kernel<<<512, 256, 0, stream>>>(Wl1, Wr1, Bfhi, Bflo);
        dim3 mgrid((Nn + 15) / 16, 2);
        gemm_mfma_kernel<<<mgrid, 256, 0, stream>>>(Ahi, Alo, Bfhi, Bflo, bl1, br1, xl, xr, Nn);
    } else {
        node_mm_kernel<256, 8><<<(Nn + 7) / 8, 256, 0, stream>>>(h, Wl1, bl1, Wr1, br1, xl, xr,
                                                                 Nn);
    }
    node_gather_kernel<false><<<gblocks, 256, 0, stream>>>(offs, esrc, nullptr, nullptr, nullptr,
                                                           att1, xl, xr, bias1, out, nullptr,
                                                           nullptr, Nn);
}